// Round 1
// baseline (1104.510 us; speedup 1.0000x reference)
//
#include <hip/hip_runtime.h>
#include <hip/hip_bf16.h>

// CrossAttention: B=4, H=W=64 (N=4096), C=512, FG=64.
// Pipeline: cast/transpose -> f,g proj (fp32, split to bf16 hi/lo)
//           -> h proj (bf16 MFMA, transposed bf16 out)
//           -> attention (split-bf16 s, exact 2-pass softmax, beta f32 out, PV bf16 MFMA)
//           -> o proj (bf16 MFMA, f32 out).

#define BATCH 4
#define NSEQ  4096
#define CHN   512
#define FGW   64
#define MROWS (BATCH * NSEQ)  // 16384

using f32x4  = __attribute__((ext_vector_type(4))) float;
using bf16x8 = __attribute__((ext_vector_type(8))) short;
using u32x4  = __attribute__((ext_vector_type(4))) unsigned int;

__device__ __forceinline__ unsigned short f2bf(float f) {
  union { __hip_bfloat16 h; unsigned short u; } v;
  v.h = __float2bfloat16(f);
  return v.u;
}
__device__ __forceinline__ float bf2f(unsigned short u) {
  return __uint_as_float(((unsigned int)u) << 16);
}
// XOR swizzle for [R][64]-ushort LDS tiles (128B rows): spreads the
// 16-lanes-same-column ds_read_b128 across all banks (guide G4 / T2).
// Bijective per row; preserves 16B alignment when c % 8 == 0.
__device__ __forceinline__ int swz(int r, int c) {
  return r * 64 + (c ^ ((r & 7) << 3));
}
__device__ __forceinline__ bf16x8 ld8(const unsigned short* base, int r, int c) {
  return *reinterpret_cast<const bf16x8*>(base + swz(r, c));
}

// ---------------- K0a: f32 -> bf16 elementwise (for l) ----------------
__global__ __launch_bounds__(256) void cast_bf16_kernel(
    const float* __restrict__ in, unsigned short* __restrict__ out) {
  int i = (blockIdx.x * 256 + threadIdx.x) * 4;
  float4 v = *reinterpret_cast<const float4*>(in + i);
  ushort4 o;
  o.x = f2bf(v.x); o.y = f2bf(v.y); o.z = f2bf(v.z); o.w = f2bf(v.w);
  *reinterpret_cast<ushort4*>(out + i) = o;
}

// ---------------- K0b: W[512][512] -> Wt[n][k] bf16 ----------------
__global__ __launch_bounds__(256) void transpose_w_kernel(
    const float* __restrict__ w, unsigned short* __restrict__ wt) {
  int t = blockIdx.x * 256 + threadIdx.x;  // 262144
  int k = t >> 9, n = t & 511;
  wt[n * 512 + k] = f2bf(w[t]);
}

// ------------- K1: f/g projection, fp32 accuracy, split hi/lo bf16 -------------
// block: 16 rows x 64 cols; thread t: col = t&63, 4 rows.
__global__ __launch_bounds__(256) void fg_proj_kernel(
    const float* __restrict__ x, const float* __restrict__ w,
    const float* __restrict__ bias,
    unsigned short* __restrict__ out_hi, unsigned short* __restrict__ out_lo) {
  __shared__ float xs[16][512];
  const int t = threadIdx.x;
  const int row0 = blockIdx.x * 16;
  {
    const float4* src = reinterpret_cast<const float4*>(x + (size_t)row0 * 512);
    float4* dst = reinterpret_cast<float4*>(&xs[0][0]);
#pragma unroll
    for (int i = 0; i < 8; i++) dst[t + i * 256] = src[t + i * 256];
  }
  __syncthreads();
  const int col = t & 63;
  const int rb = (t >> 6) * 4;
  float a0 = 0.f, a1 = 0.f, a2 = 0.f, a3 = 0.f;
#pragma unroll 8
  for (int k = 0; k < 512; k++) {
    float wv = w[k * 64 + col];        // coalesced, L2-resident (128KB)
    a0 = fmaf(xs[rb + 0][k], wv, a0);  // LDS broadcast reads
    a1 = fmaf(xs[rb + 1][k], wv, a1);
    a2 = fmaf(xs[rb + 2][k], wv, a2);
    a3 = fmaf(xs[rb + 3][k], wv, a3);
  }
  const float bv = bias[col];
  float av[4] = {a0, a1, a2, a3};
#pragma unroll
  for (int j = 0; j < 4; j++) {
    float v = fmaxf(av[j] + bv, 0.f);
    unsigned short hi = f2bf(v);
    unsigned short lo = f2bf(v - bf2f(hi));  // residual: (hi+lo) ~ fp32-accurate
    size_t idx = (size_t)(row0 + rb + j) * FGW + col;
    out_hi[idx] = hi;
    out_lo[idx] = lo;
  }
}

// ------------- K2/K4: M=16384,N=512,K=512 bf16 MFMA GEMM + bias + relu -------------
// MODE 0: out = h_t bf16 [4][512][4096] (transposed for PV B-operand)
// MODE 1: out = o f32 [16384][512] (final output)
template <int MODE>
__global__ __launch_bounds__(256) void gemm512_kernel(
    const unsigned short* __restrict__ A,   // [16384][512] bf16 row-major
    const unsigned short* __restrict__ Bt,  // [512][512] bf16, [n][k]
    const float* __restrict__ bias,         // [512]
    void* __restrict__ outp) {
  __shared__ unsigned short As[128 * 64], Bs[128 * 64];
  const int t = threadIdx.x;
  const int lane = t & 63;
  const int wid = t >> 6;
  const int wr = wid >> 1, wc = wid & 1;  // 2x2 wave grid, 64x64 each
  const int m0 = blockIdx.y * 128;
  const int n0 = blockIdx.x * 128;

  f32x4 acc[4][4] = {};
  const int srow = t >> 1;
  const int spart = (t & 1) * 32;
#pragma unroll 1
  for (int kt = 0; kt < 8; kt++) {
    const int k0 = kt * 64;
    __syncthreads();
    {
      const unsigned short* ga = A + (size_t)(m0 + srow) * 512 + k0 + spart;
      const unsigned short* gb = Bt + (size_t)(n0 + srow) * 512 + k0 + spart;
#pragma unroll
      for (int i = 0; i < 4; i++) {
        u32x4 va = *reinterpret_cast<const u32x4*>(ga + i * 8);
        u32x4 vb = *reinterpret_cast<const u32x4*>(gb + i * 8);
        *reinterpret_cast<u32x4*>(As + swz(srow, spart + i * 8)) = va;
        *reinterpret_cast<u32x4*>(Bs + swz(srow, spart + i * 8)) = vb;
      }
    }
    __syncthreads();
#pragma unroll
    for (int ks = 0; ks < 2; ks++) {
      const int koff = ks * 32 + (lane >> 4) * 8;
      bf16x8 a[4], bb[4];
#pragma unroll
      for (int rt = 0; rt < 4; rt++) a[rt] = ld8(As, wr * 64 + rt * 16 + (lane & 15), koff);
#pragma unroll
      for (int ct = 0; ct < 4; ct++) bb[ct] = ld8(Bs, wc * 64 + ct * 16 + (lane & 15), koff);
#pragma unroll
      for (int rt = 0; rt < 4; rt++)
#pragma unroll
        for (int ct = 0; ct < 4; ct++)
          acc[rt][ct] = __builtin_amdgcn_mfma_f32_16x16x32_bf16(a[rt], bb[ct], acc[rt][ct], 0, 0, 0);
    }
  }
  // epilogue: C/D layout col = lane&15, row = (lane>>4)*4 + reg
#pragma unroll
  for (int rt = 0; rt < 4; rt++)
#pragma unroll
    for (int ct = 0; ct < 4; ct++) {
      const int n = n0 + wc * 64 + ct * 16 + (lane & 15);
      const float bv = bias[n];
      const int rowb = m0 + wr * 64 + rt * 16 + (lane >> 4) * 4;
      if (MODE == 0) {
        unsigned short* ht = (unsigned short*)outp;
        const int bb2 = rowb >> 12, key = rowb & 4095;
        ushort4 v;
        v.x = f2bf(fmaxf(acc[rt][ct][0] + bv, 0.f));
        v.y = f2bf(fmaxf(acc[rt][ct][1] + bv, 0.f));
        v.z = f2bf(fmaxf(acc[rt][ct][2] + bv, 0.f));
        v.w = f2bf(fmaxf(acc[rt][ct][3] + bv, 0.f));
        *reinterpret_cast<ushort4*>(ht + ((size_t)bb2 * CHN + n) * NSEQ + key) = v;
      } else {
        float* oo = (float*)outp;
#pragma unroll
        for (int rr = 0; rr < 4; rr++)
          oo[(size_t)(rowb + rr) * CHN + n] = fmaxf(acc[rt][ct][rr] + bv, 0.f);
      }
    }
}

// ------------- K3: attention: s (split-bf16), exact softmax, beta out, PV -------------
// Block: 32 query rows of one batch, 4 waves. Wave w: s-cols [16w,16w+16) per
// 64-key block; PV cols [128w, 128w+128).
__global__ __launch_bounds__(256) void attn_kernel(
    const unsigned short* __restrict__ g_hi, const unsigned short* __restrict__ g_lo,
    const unsigned short* __restrict__ f_hi, const unsigned short* __restrict__ f_lo,
    const unsigned short* __restrict__ h_t,  // [4][512][4096] bf16
    float* __restrict__ beta_out,            // [4][4096][4096] f32
    unsigned short* __restrict__ o_att) {    // [16384][512] bf16
  __shared__ unsigned short gs_hi[32 * 64], gs_lo[32 * 64];
  __shared__ unsigned short fs_hi[64 * 64], fs_lo[64 * 64];
  __shared__ float p_f32[32][68];            // padded stride vs bank conflicts
  __shared__ unsigned short p_bf[32 * 64];
  __shared__ float m_sc[4][32], l_sc[4][32];

  const int t = threadIdx.x;
  const int lane = t & 63;
  const int w = t >> 6;
  const int bid = blockIdx.x;
  const int b = bid >> 7;
  const int q0 = (bid & 127) << 5;
  const size_t gqrow = (size_t)b * NSEQ + q0;

  // stage g rows (32x64 x {hi,lo}), contiguous 4KB each
  {
    const u32x4* shi = reinterpret_cast<const u32x4*>(g_hi + gqrow * FGW);
    const u32x4* slo = reinterpret_cast<const u32x4*>(g_lo + gqrow * FGW);
    int row = t >> 3, c8 = (t & 7) * 8;
    int di = swz(row, c8) >> 3;
    reinterpret_cast<u32x4*>(gs_hi)[di] = shi[t];
    reinterpret_cast<u32x4*>(gs_lo)[di] = slo[t];
  }
  __syncthreads();

  // A-fragments for s (kb-invariant): A[row=lane&15 + 16rt][k = 32ks + 8*(lane>>4)+i]
  bf16x8 ag_hi[2][2], ag_lo[2][2];
#pragma unroll
  for (int rt = 0; rt < 2; rt++)
#pragma unroll
    for (int ks = 0; ks < 2; ks++) {
      int koff = ks * 32 + (lane >> 4) * 8;
      ag_hi[rt][ks] = ld8(gs_hi, rt * 16 + (lane & 15), koff);
      ag_lo[rt][ks] = ld8(gs_lo, rt * 16 + (lane & 15), koff);
    }

  float m_run[2][4], l_run[2][4];
#pragma unroll
  for (int rt = 0; rt < 2; rt++)
#pragma unroll
    for (int r = 0; r < 4; r++) { m_run[rt][r] = -INFINITY; l_run[rt][r] = 0.f; }

  // ---------- pass 1: exact row max + denominator (no s storage) ----------
  for (int kb = 0; kb < 64; kb++) {
    __syncthreads();
    {
      const size_t fbase = ((size_t)b * NSEQ + kb * 64) * FGW;
      const u32x4* shi = reinterpret_cast<const u32x4*>(f_hi + fbase);
      const u32x4* slo = reinterpret_cast<const u32x4*>(f_lo + fbase);
      u32x4* dhi = reinterpret_cast<u32x4*>(fs_hi);
      u32x4* dlo = reinterpret_cast<u32x4*>(fs_lo);
#pragma unroll
      for (int i = 0; i < 2; i++) {
        int cid = t + i * 256;
        int row = cid >> 3, c8 = (cid & 7) * 8;
        int di = swz(row, c8) >> 3;
        dhi[di] = shi[cid];
        dlo[di] = slo[cid];
      }
    }
    __syncthreads();

    f32x4 sacc[2] = {};
#pragma unroll
    for (int ks = 0; ks < 2; ks++) {
      int koff = ks * 32 + (lane >> 4) * 8;
      bf16x8 bh = ld8(fs_hi, w * 16 + (lane & 15), koff);
      bf16x8 bl = ld8(fs_lo, w * 16 + (lane & 15), koff);
#pragma unroll
      for (int rt = 0; rt < 2; rt++) {
        sacc[rt] = __builtin_amdgcn_mfma_f32_16x16x32_bf16(ag_hi[rt][ks], bh, sacc[rt], 0, 0, 0);
        sacc[rt] = __builtin_amdgcn_mfma_f32_16x16x32_bf16(ag_hi[rt][ks], bl, sacc[rt], 0, 0, 0);
        sacc[rt] = __builtin_amdgcn_mfma_f32_16x16x32_bf16(ag_lo[rt][ks], bh, sacc[rt], 0, 0, 0);
      }
    }
#pragma unroll
    for (int rt = 0; rt < 2; rt++)
#pragma unroll
      for (int r = 0; r < 4; r++) {
        float s = sacc[rt][r];
        float mx = s;
        mx = fmaxf(mx, __shfl_xor(mx, 1));
        mx = fmaxf(mx, __shfl_xor(mx, 2));
        mx = fmaxf(mx, __shfl_xor(mx, 4));
        mx = fmaxf(mx, __shfl_xor(mx, 8));
        float mn = fmaxf(m_run[rt][r], mx);
        float e = __expf(s - mn);
        e += __shfl_xor(e, 1);
        e += __shfl_xor(e, 2);
        e += __shfl_xor(e, 4);
        e += __shfl_xor(e, 8);
        l_run[rt][r] = l_run[rt][r] * __expf(m_run[rt][r] - mn) + e;
        m_run[rt][r] = mn;
      }
  }

  // cross-wave merge (waves split keys, same rows)
  if ((lane & 15) == 0) {
#pragma unroll
    for (int rt = 0; rt < 2; rt++)
#pragma unroll
      for (int r = 0; r < 4; r++) {
        int row = rt * 16 + (lane >> 4) * 4 + r;
        m_sc[w][row] = m_run[rt][r];
        l_sc[w][row] = l_run[rt][r];
      }
  }
  __syncthreads();
  float m_fin[2][4], li_fin[2][4];
#pragma unroll
  for (int rt = 0; rt < 2; rt++)
#pragma unroll
    for (int r = 0; r < 4; r++) {
      int row = rt * 16 + (lane >> 4) * 4 + r;
      float mf = m_sc[0][row];
      for (int w2 = 1; w2 < 4; w2++) mf = fmaxf(mf, m_sc[w2][row]);
      float lf = 0.f;
      for (int w2 = 0; w2 < 4; w2++) lf += l_sc[w2][row] * __expf(m_sc[w2][row] - mf);
      m_fin[rt][r] = mf;
      li_fin[rt][r] = 1.f / lf;
    }

  // ---------- pass 2: recompute s, write beta, accumulate PV ----------
  f32x4 oacc[2][8] = {};
  for (int kb = 0; kb < 64; kb++) {
    __syncthreads();
    {
      const size_t fbase = ((size_t)b * NSEQ + kb * 64) * FGW;
      const u32x4* shi = reinterpret_cast<const u32x4*>(f_hi + fbase);
      const u32x4* slo = reinterpret_cast<const u32x4*>(f_lo + fbase);
      u32x4* dhi = reinterpret_cast<u32x4*>(fs_hi);
      u32x4* dlo = reinterpret_cast<u32x4*>(fs_lo);
#pragma unroll
      for (int i = 0; i < 2; i++) {
        int cid = t + i * 256;
        int row = cid >> 3, c8 = (cid & 7) * 8;
        int di = swz(row, c8) >> 3;
        dhi[di] = shi[cid];
        dlo[di] = slo[cid];
      }
    }
    __syncthreads();

    f32x4 sacc[2] = {};
#pragma unroll
    for (int ks = 0; ks < 2; ks++) {
      int koff = ks * 32 + (lane >> 4) * 8;
      bf16x8 bh = ld8(fs_hi, w * 16 + (lane & 15), koff);
      bf16x8 bl = ld8(fs_lo, w * 16 + (lane & 15), koff);
#pragma unroll
      for (int rt = 0; rt < 2; rt++) {
        sacc[rt] = __builtin_amdgcn_mfma_f32_16x16x32_bf16(ag_hi[rt][ks], bh, sacc[rt], 0, 0, 0);
        sacc[rt] = __builtin_amdgcn_mfma_f32_16x16x32_bf16(ag_hi[rt][ks], bl, sacc[rt], 0, 0, 0);
        sacc[rt] = __builtin_amdgcn_mfma_f32_16x16x32_bf16(ag_lo[rt][ks], bh, sacc[rt], 0, 0, 0);
      }
    }
#pragma unroll
    for (int rt = 0; rt < 2; rt++)
#pragma unroll
      for (int r = 0; r < 4; r++) {
        float bta = __expf(sacc[rt][r] - m_fin[rt][r]) * li_fin[rt][r];
        int row = rt * 16 + (lane >> 4) * 4 + r;
        int ck = w * 16 + (lane & 15);
        p_f32[row][ck] = bta;
        p_bf[swz(row, ck)] = f2bf(bta);
      }
    __syncthreads();

    // coalesced exact beta write: 32 rows x 64 f32
    {
      int row = t >> 3, c = (t & 7) * 8;
      float* dst = beta_out + ((size_t)(b * NSEQ + q0 + row)) * NSEQ + kb * 64 + c;
      const float* srcp = &p_f32[row][c];
      *reinterpret_cast<float4*>(dst) = *reinterpret_cast<const float4*>(srcp);
      *reinterpret_cast<float4*>(dst + 4) = *reinterpret_cast<const float4*>(srcp + 4);
    }

    // PV: oacc += p[32x64] @ h[64 keys x 512]
#pragma unroll
    for (int ks = 0; ks < 2; ks++) {
      int koff = ks * 32 + (lane >> 4) * 8;
      bf16x8 ap0 = ld8(p_bf, (lane & 15), koff);
      bf16x8 ap1 = ld8(p_bf, 16 + (lane & 15), koff);
#pragma unroll
      for (int ct = 0; ct < 8; ct++) {
        int col = w * 128 + ct * 16 + (lane & 15);
        bf16x8 bh = *reinterpret_cast<const bf16x8*>(
            h_t + ((size_t)b * CHN + col) * NSEQ + kb * 64 + koff);
        oacc[0][ct] = __builtin_amdgcn_mfma_f32_16x16x32_bf16(ap0, bh, oacc[0][ct], 0, 0, 0);
        oacc[1][ct] = __builtin_amdgcn_mfma_f32_16x16x32_bf16(ap1, bh, oacc[1][ct], 0, 0, 0);
      }
    }
  }

  // write o_att bf16 [16384][512]
#pragma unroll
  for (int rt = 0; rt < 2; rt++)
#pragma unroll
    for (int ct = 0; ct < 8; ct++) {
      int col = w * 128 + ct * 16 + (lane & 15);
#pragma unroll
      for (int r = 0; r < 4; r++) {
        int row = rt * 16 + (lane >> 4) * 4 + r;
        o_att[((size_t)(b * NSEQ + q0 + row)) * CHN + col] = f2bf(oacc[rt][ct][r]);
      }
    }
}

extern "C" void kernel_launch(void* const* d_in, const int* in_sizes, int n_in,
                              void* d_out, int out_size, void* d_ws, size_t ws_size,
                              hipStream_t stream) {
  (void)in_sizes; (void)n_in; (void)out_size; (void)ws_size;
  const float* l   = (const float*)d_in[0];
  const float* r   = (const float*)d_in[1];
  const float* wf  = (const float*)d_in[2];
  const float* wg  = (const float*)d_in[3];
  const float* wh  = (const float*)d_in[4];
  const float* wo  = (const float*)d_in[5];
  const float* bf_ = (const float*)d_in[6];
  const float* bg  = (const float*)d_in[7];
  const float* bh  = (const float*)d_in[8];
  const float* bo  = (const float*)d_in[9];

  char* ws = (char*)d_ws;  // ~58 MB used
  unsigned short* f_hi  = (unsigned short*)(ws + (0ull  << 20));
  unsigned short* f_lo  = (unsigned short*)(ws + (2ull  << 20));
  unsigned short* g_hi  = (unsigned short*)(ws + (4ull  << 20));
  unsigned short* g_lo  = (unsigned short*)(ws + (6ull  << 20));
  unsigned short* l_bf  = (unsigned short*)(ws + (8ull  << 20));  // 16 MB
  unsigned short* wh_t  = (unsigned short*)(ws + (24ull << 20));
  unsigned short* wo_t  = (unsigned short*)(ws + (25ull << 20));
  unsigned short* h_t   = (unsigned short*)(ws + (26ull << 20));  // 16 MB
  unsigned short* o_att = (unsigned short*)(ws + (42ull << 20));  // 16 MB

  float* out_o = (float*)d_out;
  float* out_beta = out_o + (size_t)MROWS * CHN;

  cast_bf16_kernel<<<MROWS * CHN / 1024, 256, 0, stream>>>(l, l_bf);
  transpose_w_kernel<<<512 * 512 / 256, 256, 0, stream>>>(wh, wh_t);
  transpose_w_kernel<<<512 * 512 / 256, 256, 0, stream>>>(wo, wo_t);
  fg_proj_kernel<<<MROWS / 16, 256, 0, stream>>>(l, wf, bf_, f_hi, f_lo);
  fg_proj_kernel<<<MROWS / 16, 256, 0, stream>>>(r, wg, bg, g_hi, g_lo);
  gemm512_kernel<0><<<dim3(4, 128), 256, 0, stream>>>(l_bf, wh_t, bh, (void*)h_t);
  attn_kernel<<<512, 256, 0, stream>>>(g_hi, g_lo, f_hi, f_lo, h_t, out_beta, o_att);
  gemm512_kernel<1><<<dim3(4, 128), 256, 0, stream>>>(o_att, wo_t, bo, (void*)out_o);
}